// Round 1
// baseline (203489.209 us; speedup 1.0000x reference)
//
#include <hip/hip_runtime.h>
#include <hip/hip_bf16.h>
#include <cmath>

#define BN_SCALE_F 0.9999950000374997f

// ---------------------------------------------------------------------------
// conv1: Cin=3, remapped input (N,seg,t,c,h,w), BN+ReLU+pool(1,2,2) fused.
// One thread per pooled output (n, co, d, oh, ow): 4 conv outputs -> max.
// ---------------------------------------------------------------------------
__global__ __launch_bounds__(256) void conv1_kernel(
    const float* __restrict__ sup, const float* __restrict__ qry,
    const float* __restrict__ wgt, const float* __restrict__ bias,
    float* __restrict__ out, int clipBase, int total)
{
    int idx = blockIdx.x * 256 + threadIdx.x;
    if (idx >= total) return;
    int ow = idx % 56; int t = idx / 56;
    int oh = t % 56; t /= 56;
    int d  = t % 16; t /= 16;
    int co = t % 64; int n = t / 64;
    int clip = clipBase + n;
    const float* src = (clip < 12) ? (sup + (size_t)clip * 602112)
                                   : (qry + (size_t)(clip - 12) * 602112);
    int h0 = 2 * oh, w0 = 2 * ow;

    bool hok[4], wok[4]; int hof[4], wcl[4];
#pragma unroll
    for (int k = 0; k < 4; k++) {
        int h = h0 - 1 + k; hok[k] = (h >= 0) && (h < 112); hof[k] = min(max(h, 0), 111) * 112;
        int w = w0 - 1 + k; wok[k] = (w >= 0) && (w < 112); wcl[k] = min(max(w, 0), 111);
    }
    bool dok[3]; int dof[3];
#pragma unroll
    for (int k = 0; k < 3; k++) {
        int dd = d - 1 + k; dok[k] = (dd >= 0) && (dd < 16);
        dof[k] = min(max(dd, 0), 15) * 37632;  // t*(3*112*112)
    }

    float acc[4] = {0.f, 0.f, 0.f, 0.f};
#pragma unroll
    for (int c = 0; c < 3; c++) {
        const float* ip = src + c * 12544;
        float wr[27];
        const float* wp = wgt + (co * 3 + c) * 27;
#pragma unroll
        for (int k = 0; k < 27; k++) wr[k] = __ldg(wp + k);
#pragma unroll
        for (int dd = 0; dd < 3; dd++) {   // plane dd corresponds to tap kd=dd
            float qv[16];
            const float* p = ip + dof[dd];
            bool dv = dok[dd];
#pragma unroll
            for (int hh = 0; hh < 4; hh++)
#pragma unroll
                for (int ww = 0; ww < 4; ww++) {
                    bool ok = dv && hok[hh] && wok[ww];
                    qv[hh * 4 + ww] = ok ? __ldg(p + hof[hh] + wcl[ww]) : 0.f;
                }
#pragma unroll
            for (int kh = 0; kh < 3; kh++)
#pragma unroll
                for (int kw = 0; kw < 3; kw++) {
                    float wv = wr[dd * 9 + kh * 3 + kw];
#pragma unroll
                    for (int dh = 0; dh < 2; dh++)
#pragma unroll
                        for (int dw = 0; dw < 2; dw++)
                            acc[dh * 2 + dw] = fmaf(wv, qv[(dh + kh) * 4 + (dw + kw)], acc[dh * 2 + dw]);
                }
        }
    }
    float b = __ldg(bias + co);
    float m = 0.f;   // relu>=0 so max-init 0 is exact
#pragma unroll
    for (int k = 0; k < 4; k++) {
        float y = (acc[k] + b) * BN_SCALE_F;
        m = fmaxf(m, y);
    }
    out[idx] = m;
}

// ---------------------------------------------------------------------------
// Generic 'b'-layer: conv3x3x3 + BN + ReLU + maxpool(2,2,2) fused.
// PADHW=1 only for conv5b (pool pad (0,1,1)). One thread per pooled output.
// ---------------------------------------------------------------------------
template <int PADHW>
__global__ __launch_bounds__(256) void convb_pool_kernel(
    const float* __restrict__ in, const float* __restrict__ wgt,
    const float* __restrict__ bias, float* __restrict__ out,
    int Cin, int Cout, int D, int H, int W,
    int OD, int OH, int OW, int total)
{
    int idx = blockIdx.x * 256 + threadIdx.x;
    if (idx >= total) return;
    int ow = idx % OW; int t = idx / OW;
    int oh = t % OH; t /= OH;
    int od = t % OD; t /= OD;
    int co = t % Cout; int n = t / Cout;
    int d0 = 2 * od, h0 = 2 * oh - PADHW, w0 = 2 * ow - PADHW;
    const int HW = H * W, DHW = D * HW;

    bool hok[4], wok[4]; int hof[4], wcl[4];
#pragma unroll
    for (int k = 0; k < 4; k++) {
        int h = h0 - 1 + k; hok[k] = (h >= 0) && (h < H); hof[k] = min(max(h, 0), H - 1) * W;
        int w = w0 - 1 + k; wok[k] = (w >= 0) && (w < W); wcl[k] = min(max(w, 0), W - 1);
    }
    bool dok[4]; int dof[4];
#pragma unroll
    for (int k = 0; k < 4; k++) {
        int dd = d0 - 1 + k; dok[k] = (dd >= 0) && (dd < D); dof[k] = min(max(dd, 0), D - 1) * HW;
    }

    const float* inb = in + (size_t)n * Cin * DHW;
    const float* wb  = wgt + (size_t)co * Cin * 27;
    float acc[8] = {0.f, 0.f, 0.f, 0.f, 0.f, 0.f, 0.f, 0.f};

    for (int ci = 0; ci < Cin; ci++) {
        const float* ip = inb + (size_t)ci * DHW;
        const float* wp = wb + ci * 27;
        float wr[27];
#pragma unroll
        for (int k = 0; k < 27; k++) wr[k] = __ldg(wp + k);
#pragma unroll
        for (int dd = 0; dd < 4; dd++) {
            float qv[16];
            const float* p = ip + dof[dd];
            bool dv = dok[dd];
#pragma unroll
            for (int hh = 0; hh < 4; hh++)
#pragma unroll
                for (int ww = 0; ww < 4; ww++) {
                    bool ok = dv && hok[hh] && wok[ww];
                    qv[hh * 4 + ww] = ok ? __ldg(p + hof[hh] + wcl[ww]) : 0.f;
                }
#pragma unroll
            for (int kd = 0; kd < 3; kd++) {
                int deltad = dd - kd;            // conv-out d offset within pool window
                if (deltad < 0 || deltad > 1) continue;
#pragma unroll
                for (int kh = 0; kh < 3; kh++)
#pragma unroll
                    for (int kw = 0; kw < 3; kw++) {
                        float wv = wr[kd * 9 + kh * 3 + kw];
#pragma unroll
                        for (int dh = 0; dh < 2; dh++)
#pragma unroll
                            for (int dw = 0; dw < 2; dw++)
                                acc[deltad * 4 + dh * 2 + dw] =
                                    fmaf(wv, qv[(dh + kh) * 4 + (dw + kw)], acc[deltad * 4 + dh * 2 + dw]);
                    }
            }
        }
    }
    float b = __ldg(bias + co);
    float m = 0.f;
#pragma unroll
    for (int dd2 = 0; dd2 < 2; dd2++)
#pragma unroll
        for (int dh = 0; dh < 2; dh++) {
            if (PADHW && (h0 + dh < 0 || h0 + dh >= H)) continue;
#pragma unroll
            for (int dw = 0; dw < 2; dw++) {
                if (PADHW && (w0 + dw < 0 || w0 + dw >= W)) continue;
                float y = (acc[dd2 * 4 + dh * 2 + dw] + b) * BN_SCALE_F;
                m = fmaxf(m, y);
            }
        }
    out[idx] = m;
}

// ---------------------------------------------------------------------------
// 'a'-layer: plain conv3x3x3 + ReLU (no BN, no pool). Thread computes a
// strip of 4 outputs along w.
// ---------------------------------------------------------------------------
__global__ __launch_bounds__(256) void conva_kernel(
    const float* __restrict__ in, const float* __restrict__ wgt,
    const float* __restrict__ bias, float* __restrict__ out,
    int Cin, int Cout, int D, int H, int W, int WS, int total)
{
    int idx = blockIdx.x * 256 + threadIdx.x;
    if (idx >= total) return;
    int wq = idx % WS; int t = idx / WS;
    int h = t % H; t /= H;
    int d = t % D; t /= D;
    int co = t % Cout; int n = t / Cout;
    int w0 = wq * 4;
    const int HW = H * W, DHW = D * HW;

    bool hok[3]; int hof[3];
#pragma unroll
    for (int k = 0; k < 3; k++) { int hh = h - 1 + k; hok[k] = (hh >= 0) && (hh < H); hof[k] = min(max(hh, 0), H - 1) * W; }
    bool dok[3]; int dof[3];
#pragma unroll
    for (int k = 0; k < 3; k++) { int dd = d - 1 + k; dok[k] = (dd >= 0) && (dd < D); dof[k] = min(max(dd, 0), D - 1) * HW; }
    bool wok[6]; int wcl[6];
#pragma unroll
    for (int k = 0; k < 6; k++) { int ww = w0 - 1 + k; wok[k] = (ww >= 0) && (ww < W); wcl[k] = min(max(ww, 0), W - 1); }

    const float* inb = in + (size_t)n * Cin * DHW;
    const float* wb  = wgt + (size_t)co * Cin * 27;
    float acc[4] = {0.f, 0.f, 0.f, 0.f};

    for (int ci = 0; ci < Cin; ci++) {
        const float* ip = inb + (size_t)ci * DHW;
        float wr[27];
#pragma unroll
        for (int k = 0; k < 27; k++) wr[k] = __ldg(wb + ci * 27 + k);
#pragma unroll
        for (int dd = 0; dd < 3; dd++)
#pragma unroll
            for (int hh = 0; hh < 3; hh++) {
                float qv[6];
                bool rv = dok[dd] && hok[hh];
                const float* p = ip + dof[dd] + hof[hh];
#pragma unroll
                for (int k = 0; k < 6; k++) qv[k] = (rv && wok[k]) ? __ldg(p + wcl[k]) : 0.f;
#pragma unroll
                for (int kw = 0; kw < 3; kw++) {
                    float wv = wr[dd * 9 + hh * 3 + kw];
#pragma unroll
                    for (int t4 = 0; t4 < 4; t4++)
                        acc[t4] = fmaf(wv, qv[t4 + kw], acc[t4]);
                }
            }
    }
    float b = __ldg(bias + co);
    float* op = out + (((size_t)(n * Cout + co) * D + d) * H + h) * W;
#pragma unroll
    for (int t4 = 0; t4 < 4; t4++) {
        int w = w0 + t4;
        if (w < W) op[w] = fmaxf(acc[t4] + b, 0.f);
    }
}

// ---------------------------------------------------------------------------
// FC: out[n][co] = relu(BN*(x[n].W[co] + b[co])). One wave per output.
// ---------------------------------------------------------------------------
__global__ __launch_bounds__(256) void fc_kernel(
    const float* __restrict__ x, const float* __restrict__ wgt,
    const float* __restrict__ bias, float* __restrict__ out,
    int K, int Cout, int total)
{
    int gt = blockIdx.x * 256 + threadIdx.x;
    int wid = gt >> 6;
    int lane = gt & 63;
    if (wid >= total) return;
    int co = wid % Cout; int n = wid / Cout;
    const float4* xp = (const float4*)(x + (size_t)n * K);
    const float4* wp = (const float4*)(wgt + (size_t)co * K);
    int K4 = K >> 2;
    float s = 0.f;
    for (int k = lane; k < K4; k += 64) {
        float4 a = __ldg(xp + k), b = __ldg(wp + k);
        s += a.x * b.x + a.y * b.y + a.z * b.z + a.w * b.w;
    }
#pragma unroll
    for (int off = 32; off > 0; off >>= 1) s += __shfl_down(s, off, 64);
    if (lane == 0) {
        float y = (s + __ldg(bias + co)) * BN_SCALE_F;
        out[wid] = fmaxf(y, 0.f);
    }
}

// ---------------------------------------------------------------------------
// Head phase A: 168 reductions over 4096-d rows of feat (24 norms^2 + 144 dots)
// ---------------------------------------------------------------------------
__global__ __launch_bounds__(256) void dots_kernel(
    const float* __restrict__ feat, float* __restrict__ dots)
{
    int task = blockIdx.x; int tid = threadIdx.x;
    int ra, rb;
    if (task < 24) { ra = task; rb = task; }
    else {
        int t = task - 24;
        int q = t / 48; int r = t % 48;
        int i = r / 12; int s = (r % 12) / 4; int j = r % 4;
        ra = 12 + q * 4 + i;  // query row
        rb = s * 4 + j;       // support row
    }
    const float4* A = (const float4*)(feat + (size_t)ra * 4096);
    const float4* B = (const float4*)(feat + (size_t)rb * 4096);
    float acc = 0.f;
    for (int k = tid; k < 1024; k += 256) {
        float4 a = A[k], b = B[k];
        acc += a.x * b.x + a.y * b.y + a.z * b.z + a.w * b.w;
    }
#pragma unroll
    for (int off = 32; off > 0; off >>= 1) acc += __shfl_down(acc, off, 64);
    __shared__ float red[4];
    if ((tid & 63) == 0) red[tid >> 6] = acc;
    __syncthreads();
    if (tid == 0) dots[task] = red[0] + red[1] + red[2] + red[3];
}

// ---------------------------------------------------------------------------
// Head phase B: Sinkhorn (100 iters) per (q,s) pair entirely in registers.
// ---------------------------------------------------------------------------
__global__ __launch_bounds__(64) void sinkhorn_kernel(
    const float* __restrict__ dots, float* __restrict__ out)
{
    int t = threadIdx.x;
    if (t >= 9) return;
    int q = t / 3, s = t % 3;
    float Km[16], sem[16];
#pragma unroll
    for (int i = 0; i < 4; i++) {
        float nq = sqrtf(dots[12 + q * 4 + i]) + 1e-8f;
#pragma unroll
        for (int j = 0; j < 4; j++) {
            float ns = sqrtf(dots[s * 4 + j]) + 1e-8f;
            float d = dots[24 + q * 48 + i * 12 + s * 4 + j];
            float c = 1.0f - d / (nq * ns);
            float ti = i * 0.25f, tj = j * 0.25f;
            float d2 = (ti - tj) * (ti - tj);
            float pc = expf(-1.0f / (d2 + 1.0f));   // PHI=1
            sem[i * 4 + j] = c;
            Km[i * 4 + j] = expf(-7.0f * (c + 0.4f * pc));  // REG=7, ALPHA=0.4
        }
    }
    float u[4] = {0.25f, 0.25f, 0.25f, 0.25f}, v[4];
    for (int it = 0; it < 100; it++) {
#pragma unroll
        for (int j = 0; j < 4; j++) {
            float sj = Km[j] * u[0] + Km[4 + j] * u[1] + Km[8 + j] * u[2] + Km[12 + j] * u[3];
            v[j] = 0.25f / (sj + 1e-9f);
        }
#pragma unroll
        for (int i = 0; i < 4; i++) {
            float si = Km[i * 4] * v[0] + Km[i * 4 + 1] * v[1] + Km[i * 4 + 2] * v[2] + Km[i * 4 + 3] * v[3];
            u[i] = 0.25f / (si + 1e-9f);
        }
    }
#pragma unroll
    for (int j = 0; j < 4; j++) {
        float sj = Km[j] * u[0] + Km[4 + j] * u[1] + Km[8 + j] * u[2] + Km[12 + j] * u[3];
        v[j] = 0.25f / (sj + 1e-9f);
    }
    float tc = 0.f;
#pragma unroll
    for (int i = 0; i < 4; i++)
#pragma unroll
        for (int j = 0; j < 4; j++)
            tc += u[i] * Km[i * 4 + j] * v[j] * sem[i * 4 + j];
    out[q * 3 + s] = -tc;
}

// ---------------------------------------------------------------------------
extern "C" void kernel_launch(void* const* d_in, const int* in_sizes, int n_in,
                              void* d_out, int out_size, void* d_ws, size_t ws_size,
                              hipStream_t stream)
{
    const float* sup = (const float*)d_in[0];
    const float* qry = (const float*)d_in[1];
    const float* w1  = (const float*)d_in[2];  const float* b1  = (const float*)d_in[3];
    const float* w2  = (const float*)d_in[4];  const float* b2  = (const float*)d_in[5];
    const float* w3a = (const float*)d_in[6];  const float* b3a = (const float*)d_in[7];
    const float* w3b = (const float*)d_in[8];  const float* b3b = (const float*)d_in[9];
    const float* w4a = (const float*)d_in[10]; const float* b4a = (const float*)d_in[11];
    const float* w4b = (const float*)d_in[12]; const float* b4b = (const float*)d_in[13];
    const float* w5a = (const float*)d_in[14]; const float* b5a = (const float*)d_in[15];
    const float* w5b = (const float*)d_in[16]; const float* b5b = (const float*)d_in[17];
    const float* w6  = (const float*)d_in[18]; const float* b6  = (const float*)d_in[19];
    const float* w7  = (const float*)d_in[20]; const float* b7  = (const float*)d_in[21];
    float* out = (float*)d_out;

    // per-clip region sizes (floats)
    const long long SA = 3211264LL;  // conv1p out (also holds conv3a out, fc6 out)
    const long long SB = 802816LL;   // conv2p out (also x3bp, x5a)
    const long long SC = 401408LL;   // conv4a out (also x5bp)
    const long long SD = 50176LL;    // conv4bp out
    const long long perclip = SA + SB + SC + SD;       // 4,465,664
    const long long persist = 98304LL + 256LL;         // feat(24x4096) + dots

    int G = 1;
    const int cands[8] = {24, 12, 8, 6, 4, 3, 2, 1};
    for (int k = 0; k < 8; k++) {
        long long need = (perclip * cands[k] + persist) * 4;
        if (need <= (long long)ws_size) { G = cands[k]; break; }
    }

    float* ws = (float*)d_ws;
    float* RA = ws;
    float* RB = RA + (size_t)(SA * G);
    float* RC = RB + (size_t)(SB * G);
    float* RD = RC + (size_t)(SC * G);
    float* feat  = ws + (size_t)(perclip * G);
    float* dotsb = feat + 98304;

    for (int base = 0; base < 24; base += G) {
        int total1 = G * 64 * 16 * 56 * 56;
        conv1_kernel<<<(total1 + 255) / 256, 256, 0, stream>>>(sup, qry, w1, b1, RA, base, total1);

        int total2 = G * 128 * 8 * 28 * 28;
        convb_pool_kernel<0><<<(total2 + 255) / 256, 256, 0, stream>>>(
            RA, w2, b2, RB, 64, 128, 16, 56, 56, 8, 28, 28, total2);

        int total3a = G * 256 * 8 * 28 * 7;   // WS = 28/4 = 7
        conva_kernel<<<(total3a + 255) / 256, 256, 0, stream>>>(
            RB, w3a, b3a, RA, 128, 256, 8, 28, 28, 7, total3a);

        int total3b = G * 256 * 4 * 14 * 14;
        convb_pool_kernel<0><<<(total3b + 255) / 256, 256, 0, stream>>>(
            RA, w3b, b3b, RB, 256, 256, 8, 28, 28, 4, 14, 14, total3b);

        int total4a = G * 512 * 4 * 14 * 4;   // WS = ceil(14/4) = 4
        conva_kernel<<<(total4a + 255) / 256, 256, 0, stream>>>(
            RB, w4a, b4a, RC, 256, 512, 4, 14, 14, 4, total4a);

        int total4b = G * 512 * 2 * 7 * 7;
        convb_pool_kernel<0><<<(total4b + 255) / 256, 256, 0, stream>>>(
            RC, w4b, b4b, RD, 512, 512, 4, 14, 14, 2, 7, 7, total4b);

        int total5a = G * 512 * 2 * 7 * 2;    // WS = ceil(7/4) = 2
        conva_kernel<<<(total5a + 255) / 256, 256, 0, stream>>>(
            RD, w5a, b5a, RB, 512, 512, 2, 7, 7, 2, total5a);

        int total5b = G * 512 * 1 * 4 * 4;
        convb_pool_kernel<1><<<(total5b + 255) / 256, 256, 0, stream>>>(
            RB, w5b, b5b, RC, 512, 512, 2, 7, 7, 1, 4, 4, total5b);

        int t6 = G * 4096;
        fc_kernel<<<(t6 * 64 + 255) / 256, 256, 0, stream>>>(RC, w6, b6, RA, 8192, 4096, t6);
        fc_kernel<<<(t6 * 64 + 255) / 256, 256, 0, stream>>>(RA, w7, b7,
                                                             feat + (size_t)base * 4096, 4096, 4096, t6);
    }

    dots_kernel<<<168, 256, 0, stream>>>(feat, dotsb);
    sinkhorn_kernel<<<1, 64, 0, stream>>>(dotsb, out);
}

// Round 2
// 43077.170 us; speedup vs baseline: 4.7238x; 4.7238x over previous
//
#include <hip/hip_runtime.h>
#include <hip/hip_bf16.h>
#include <cmath>

#define BN_SCALE_F 0.9999950000374997f

// ---------------------------------------------------------------------------
// Unified tiled 3x3x3 conv.
// MODE 0: 'a' layer  — conv + ReLU, store 8 outputs (2x2x2)
// MODE 1: 'b' layer  — conv + BN + ReLU + maxpool(2,2,2), 1 pooled out/thread
// MODE 2: conv1      — raw clip input (t,c,h,w), BN + ReLU + pool(1,2,2),
//                      2 pooled outs/thread
// MODE 3: conv5b     — like MODE 1 but pool pad (0,1,1)
// Block: 16 co x 16 spatial threads; conv region (2,8,8); input patch
// (4,10,10)+pad staged in LDS per 2-channel chunk together with 16x27 weights.
// ---------------------------------------------------------------------------
template<int CIN,int COUT,int D,int H,int W,int MODE>
__global__ __launch_bounds__(256) void conv_tile(
    const float* __restrict__ in,
    const float* __restrict__ sup, const float* __restrict__ qry, int clipBase,
    const float* __restrict__ wgt, const float* __restrict__ bias,
    float* __restrict__ out)
{
    constexpr int PAD = (MODE == 3) ? 1 : 0;
    constexpr int OD  = (MODE == 0 || MODE == 2) ? D : D / 2;
    constexpr int OH  = (MODE == 0) ? H : (H + 2 * PAD) / 2;
    constexpr int OW  = (MODE == 0) ? W : (W + 2 * PAD) / 2;
    constexpr int TH  = (MODE == 0) ? (H + 7) / 8 : (OH + 3) / 4;
    constexpr int TW  = (MODE == 0) ? (W + 7) / 8 : (OW + 3) / 4;
    constexpr int HW  = H * W;
    constexpr int CC  = (CIN % 2 == 0) ? 2 : 1;   // channels per LDS stage

    __shared__ float sIn[CC][4][10][12];
    __shared__ float sW[CC][16][28];

    const int tid = threadIdx.x;
    const int bw = blockIdx.x % TW;
    const int bh = (blockIdx.x / TW) % TH;
    const int bd = blockIdx.x / (TW * TH);
    const int coL = tid >> 4;
    const int co  = blockIdx.y * 16 + coL;
    const int sp  = tid & 15;
    const int sh = sp >> 2, sw = sp & 3;
    const int n = blockIdx.z;

    const int d0 = 2 * bd, h0 = 8 * bh - PAD, w0 = 8 * bw - PAD;
    const int ht = h0 + 2 * sh, wt = w0 + 2 * sw;

    const float* src;
    if constexpr (MODE == 2) {
        int clip = clipBase + n;
        src = (clip < 12) ? (sup + (size_t)clip * 602112)
                          : (qry + (size_t)(clip - 12) * 602112);
    } else {
        src = in + (size_t)n * CIN * D * HW;
    }

    float acc[8] = {0.f, 0.f, 0.f, 0.f, 0.f, 0.f, 0.f, 0.f};

    for (int ci0 = 0; ci0 < CIN; ci0 += CC) {
        // ---- stage input patch + weights into LDS ----
        for (int t = tid; t < CC * 400 + CC * 432; t += 256) {
            if (t < CC * 400) {
                int c = t / 400, r = t % 400;
                int pd = r / 100, ph = (r / 10) % 10, pw = r % 10;
                int gd = d0 - 1 + pd, gh = h0 - 1 + ph, gw = w0 - 1 + pw;
                float v = 0.f;
                if (gd >= 0 && gd < D && gh >= 0 && gh < H && gw >= 0 && gw < W) {
                    if constexpr (MODE == 2)
                        v = src[(size_t)gd * 37632 + (ci0 + c) * 12544 + gh * 112 + gw];
                    else
                        v = src[(size_t)(ci0 + c) * D * HW + gd * HW + gh * W + gw];
                }
                sIn[c][pd][ph][pw] = v;
            } else {
                int t2 = t - CC * 400;
                int c = t2 / 432, r = t2 % 432;
                int cl = r / 27, k = r % 27;
                sW[c][cl][k] = wgt[((size_t)(blockIdx.y * 16 + cl) * CIN + (ci0 + c)) * 27 + k];
            }
        }
        __syncthreads();
        // ---- compute ----
        for (int c = 0; c < CC; c++) {
            float wr[27];
#pragma unroll
            for (int k = 0; k < 27; k++) wr[k] = sW[c][coL][k];
#pragma unroll
            for (int dd = 0; dd < 4; dd++) {
                float qv[16];
#pragma unroll
                for (int hh = 0; hh < 4; hh++)
#pragma unroll
                    for (int ww = 0; ww < 4; ww++)
                        qv[hh * 4 + ww] = sIn[c][dd][2 * sh + hh][2 * sw + ww];
#pragma unroll
                for (int kd = 0; kd < 3; kd++) {
                    int deltad = dd - kd;
                    if (deltad < 0 || deltad > 1) continue;
#pragma unroll
                    for (int kh = 0; kh < 3; kh++)
#pragma unroll
                        for (int kw = 0; kw < 3; kw++) {
                            float wv = wr[kd * 9 + kh * 3 + kw];
#pragma unroll
                            for (int dh = 0; dh < 2; dh++)
#pragma unroll
                                for (int dw = 0; dw < 2; dw++)
                                    acc[deltad * 4 + dh * 2 + dw] =
                                        fmaf(wv, qv[(dh + kh) * 4 + (dw + kw)],
                                             acc[deltad * 4 + dh * 2 + dw]);
                        }
                }
            }
        }
        __syncthreads();
    }

    const float b = __ldg(bias + co);
    if constexpr (MODE == 0) {
#pragma unroll
        for (int dd = 0; dd < 2; dd++) {
            int d = d0 + dd; if (d >= D) continue;
#pragma unroll
            for (int dh = 0; dh < 2; dh++) {
                int h = ht + dh; if (h < 0 || h >= H) continue;
#pragma unroll
                for (int dw = 0; dw < 2; dw++) {
                    int w = wt + dw; if (w < 0 || w >= W) continue;
                    out[(((size_t)n * COUT + co) * D + d) * HW + h * W + w] =
                        fmaxf(acc[dd * 4 + dh * 2 + dw] + b, 0.f);
                }
            }
        }
    } else if constexpr (MODE == 2) {
        int oh = 4 * bh + sh, ow = 4 * bw + sw;   // exact (112 divisible)
#pragma unroll
        for (int dd = 0; dd < 2; dd++) {
            float m = 0.f;
#pragma unroll
            for (int k = 0; k < 4; k++) m = fmaxf(m, (acc[dd * 4 + k] + b) * BN_SCALE_F);
            out[(((size_t)n * COUT + co) * OD + (d0 + dd)) * (OH * OW) + oh * OW + ow] = m;
        }
    } else {
        int oh = 4 * bh + sh, ow = 4 * bw + sw;
        if (oh < OH && ow < OW) {
            float m = 0.f;
#pragma unroll
            for (int dd = 0; dd < 2; dd++)
#pragma unroll
                for (int dh = 0; dh < 2; dh++) {
                    int h = ht + dh; if (PAD && (h < 0 || h >= H)) continue;
#pragma unroll
                    for (int dw = 0; dw < 2; dw++) {
                        int w = wt + dw; if (PAD && (w < 0 || w >= W)) continue;
                        m = fmaxf(m, (acc[dd * 4 + dh * 2 + dw] + b) * BN_SCALE_F);
                    }
                }
            out[(((size_t)n * COUT + co) * OD + bd) * (OH * OW) + oh * OW + ow] = m;
        }
    }
}

// ---------------------------------------------------------------------------
// FC: out[n][co] = relu(BN*(x[n].W[co] + b[co])). One wave per output.
// ---------------------------------------------------------------------------
__global__ __launch_bounds__(256) void fc_kernel(
    const float* __restrict__ x, const float* __restrict__ wgt,
    const float* __restrict__ bias, float* __restrict__ out,
    int K, int Cout, int total)
{
    int gt = blockIdx.x * 256 + threadIdx.x;
    int wid = gt >> 6;
    int lane = gt & 63;
    if (wid >= total) return;
    int co = wid % Cout; int n = wid / Cout;
    const float4* xp = (const float4*)(x + (size_t)n * K);
    const float4* wp = (const float4*)(wgt + (size_t)co * K);
    int K4 = K >> 2;
    float s = 0.f;
    for (int k = lane; k < K4; k += 64) {
        float4 a = __ldg(xp + k), b = __ldg(wp + k);
        s += a.x * b.x + a.y * b.y + a.z * b.z + a.w * b.w;
    }
#pragma unroll
    for (int off = 32; off > 0; off >>= 1) s += __shfl_down(s, off, 64);
    if (lane == 0) {
        float y = (s + __ldg(bias + co)) * BN_SCALE_F;
        out[wid] = fmaxf(y, 0.f);
    }
}

// ---------------------------------------------------------------------------
// Head phase A: 168 reductions over 4096-d rows (24 norms^2 + 144 dots)
// ---------------------------------------------------------------------------
__global__ __launch_bounds__(256) void dots_kernel(
    const float* __restrict__ feat, float* __restrict__ dots)
{
    int task = blockIdx.x; int tid = threadIdx.x;
    int ra, rb;
    if (task < 24) { ra = task; rb = task; }
    else {
        int t = task - 24;
        int q = t / 48; int r = t % 48;
        int i = r / 12; int s = (r % 12) / 4; int j = r % 4;
        ra = 12 + q * 4 + i;
        rb = s * 4 + j;
    }
    const float4* A = (const float4*)(feat + (size_t)ra * 4096);
    const float4* B = (const float4*)(feat + (size_t)rb * 4096);
    float acc = 0.f;
    for (int k = tid; k < 1024; k += 256) {
        float4 a = A[k], b = B[k];
        acc += a.x * b.x + a.y * b.y + a.z * b.z + a.w * b.w;
    }
#pragma unroll
    for (int off = 32; off > 0; off >>= 1) acc += __shfl_down(acc, off, 64);
    __shared__ float red[4];
    if ((tid & 63) == 0) red[tid >> 6] = acc;
    __syncthreads();
    if (tid == 0) dots[task] = red[0] + red[1] + red[2] + red[3];
}

// ---------------------------------------------------------------------------
// Head phase B: Sinkhorn (100 iters) per (q,s) pair entirely in registers.
// ---------------------------------------------------------------------------
__global__ __launch_bounds__(64) void sinkhorn_kernel(
    const float* __restrict__ dots, float* __restrict__ out)
{
    int t = threadIdx.x;
    if (t >= 9) return;
    int q = t / 3, s = t % 3;
    float Km[16], sem[16];
#pragma unroll
    for (int i = 0; i < 4; i++) {
        float nq = sqrtf(dots[12 + q * 4 + i]) + 1e-8f;
#pragma unroll
        for (int j = 0; j < 4; j++) {
            float ns = sqrtf(dots[s * 4 + j]) + 1e-8f;
            float d = dots[24 + q * 48 + i * 12 + s * 4 + j];
            float c = 1.0f - d / (nq * ns);
            float ti = i * 0.25f, tj = j * 0.25f;
            float d2 = (ti - tj) * (ti - tj);
            float pc = expf(-1.0f / (d2 + 1.0f));
            sem[i * 4 + j] = c;
            Km[i * 4 + j] = expf(-7.0f * (c + 0.4f * pc));
        }
    }
    float u[4] = {0.25f, 0.25f, 0.25f, 0.25f}, v[4];
    for (int it = 0; it < 100; it++) {
#pragma unroll
        for (int j = 0; j < 4; j++) {
            float sj = Km[j] * u[0] + Km[4 + j] * u[1] + Km[8 + j] * u[2] + Km[12 + j] * u[3];
            v[j] = 0.25f / (sj + 1e-9f);
        }
#pragma unroll
        for (int i = 0; i < 4; i++) {
            float si = Km[i * 4] * v[0] + Km[i * 4 + 1] * v[1] + Km[i * 4 + 2] * v[2] + Km[i * 4 + 3] * v[3];
            u[i] = 0.25f / (si + 1e-9f);
        }
    }
#pragma unroll
    for (int j = 0; j < 4; j++) {
        float sj = Km[j] * u[0] + Km[4 + j] * u[1] + Km[8 + j] * u[2] + Km[12 + j] * u[3];
        v[j] = 0.25f / (sj + 1e-9f);
    }
    float tc = 0.f;
#pragma unroll
    for (int i = 0; i < 4; i++)
#pragma unroll
        for (int j = 0; j < 4; j++)
            tc += u[i] * Km[i * 4 + j] * v[j] * sem[i * 4 + j];
    out[q * 3 + s] = -tc;
}

// ---------------------------------------------------------------------------
extern "C" void kernel_launch(void* const* d_in, const int* in_sizes, int n_in,
                              void* d_out, int out_size, void* d_ws, size_t ws_size,
                              hipStream_t stream)
{
    const float* sup = (const float*)d_in[0];
    const float* qry = (const float*)d_in[1];
    const float* w1  = (const float*)d_in[2];  const float* b1  = (const float*)d_in[3];
    const float* w2  = (const float*)d_in[4];  const float* b2  = (const float*)d_in[5];
    const float* w3a = (const float*)d_in[6];  const float* b3a = (const float*)d_in[7];
    const float* w3b = (const float*)d_in[8];  const float* b3b = (const float*)d_in[9];
    const float* w4a = (const float*)d_in[10]; const float* b4a = (const float*)d_in[11];
    const float* w4b = (const float*)d_in[12]; const float* b4b = (const float*)d_in[13];
    const float* w5a = (const float*)d_in[14]; const float* b5a = (const float*)d_in[15];
    const float* w5b = (const float*)d_in[16]; const float* b5b = (const float*)d_in[17];
    const float* w6  = (const float*)d_in[18]; const float* b6  = (const float*)d_in[19];
    const float* w7  = (const float*)d_in[20]; const float* b7  = (const float*)d_in[21];
    float* out = (float*)d_out;
    float* ws = (float*)d_ws;

    // per-clip buffer sizes (floats)
    const long long S1 = 3211264, S2 = 802816, S3a = 1605632;
    const long long ST1 = S1 + S2;                 // stage-1 scratch peak/clip
    const long long CL4 = 50176, CL5a = 50176, CL5b = 8192;

    // Mode A: batched tail (conv5a..head over all 24 clips at once).
    const long long persistA = 24 * (CL4 + CL5a + CL5b + 4096 + 4096) + 256;
    int G = 0;
    const int cands[8] = {24, 12, 8, 6, 4, 3, 2, 1};
    for (int k = 0; k < 8; k++) {
        long long need = (ST1 * cands[k] + persistA) * 4;
        if (need <= (long long)ws_size) { G = cands[k]; break; }
    }

    if (G > 0) {
        float* x1p  = ws;                               // G * S1
        float* x2p  = ws + (size_t)G * S1;              // G * S2
        float* x3a  = ws;                               // G * S3a  (over dead x1p)
        float* x3bp = ws + (size_t)G * S3a;             // G * 200704
        float* x4a  = ws;                               // G * 401408 (over dead x3a)
        float* P     = ws + (size_t)G * ST1;
        float* x4b24 = P;
        float* x5a24 = x4b24 + 24 * CL4;
        float* x5b24 = x5a24 + 24 * CL5a;
        float* fc6o  = x5b24 + 24 * CL5b;
        float* feat  = fc6o + 24 * 4096;
        float* dotsb = feat + 24 * 4096;

        for (int base = 0; base < 24; base += G) {
            dim3 g1(1568, 4, G);
            conv_tile<3, 64, 16, 112, 112, 2><<<g1, 256, 0, stream>>>(
                nullptr, sup, qry, base, w1, b1, x1p);
            dim3 g2(392, 8, G);
            conv_tile<64, 128, 16, 56, 56, 1><<<g2, 256, 0, stream>>>(
                x1p, nullptr, nullptr, 0, w2, b2, x2p);
            dim3 g3a(64, 16, G);
            conv_tile<128, 256, 8, 28, 28, 0><<<g3a, 256, 0, stream>>>(
                x2p, nullptr, nullptr, 0, w3a, b3a, x3a);
            dim3 g3b(64, 16, G);
            conv_tile<256, 256, 8, 28, 28, 1><<<g3b, 256, 0, stream>>>(
                x3a, nullptr, nullptr, 0, w3b, b3b, x3bp);
            dim3 g4a(8, 32, G);
            conv_tile<256, 512, 4, 14, 14, 0><<<g4a, 256, 0, stream>>>(
                x3bp, nullptr, nullptr, 0, w4a, b4a, x4a);
            dim3 g4b(8, 32, G);
            conv_tile<512, 512, 4, 14, 14, 1><<<g4b, 256, 0, stream>>>(
                x4a, nullptr, nullptr, 0, w4b, b4b, x4b24 + (size_t)base * CL4);
        }
        dim3 g5a(1, 32, 24);
        conv_tile<512, 512, 2, 7, 7, 0><<<g5a, 256, 0, stream>>>(
            x4b24, nullptr, nullptr, 0, w5a, b5a, x5a24);
        dim3 g5b(1, 32, 24);
        conv_tile<512, 512, 2, 7, 7, 3><<<g5b, 256, 0, stream>>>(
            x5a24, nullptr, nullptr, 0, w5b, b5b, x5b24);
        int t6 = 24 * 4096;
        fc_kernel<<<(t6 * 64 + 255) / 256, 256, 0, stream>>>(x5b24, w6, b6, fc6o, 8192, 4096, t6);
        fc_kernel<<<(t6 * 64 + 255) / 256, 256, 0, stream>>>(fc6o, w7, b7, feat, 4096, 4096, t6);
        dots_kernel<<<168, 256, 0, stream>>>(feat, dotsb);
        sinkhorn_kernel<<<1, 64, 0, stream>>>(dotsb, out);
    } else {
        // Mode B: fully per-clip (needs only ~16.9 MB of workspace)
        float* x1p  = ws;
        float* x2p  = ws + S1;
        float* x3a  = ws;
        float* x3bp = ws + S3a;
        float* x4a  = ws;
        float* x4bp = ws + ST1;
        float* x5a  = x4bp + CL4;
        float* x5bp = x5a + CL5a;
        float* fc6o = x5bp + CL5b;
        float* feat = fc6o + 4096;
        float* dotsb = feat + 24 * 4096;

        for (int clip = 0; clip < 24; clip++) {
            dim3 g1(1568, 4, 1);
            conv_tile<3, 64, 16, 112, 112, 2><<<g1, 256, 0, stream>>>(
                nullptr, sup, qry, clip, w1, b1, x1p);
            dim3 g2(392, 8, 1);
            conv_tile<64, 128, 16, 56, 56, 1><<<g2, 256, 0, stream>>>(
                x1p, nullptr, nullptr, 0, w2, b2, x2p);
            dim3 g3a(64, 16, 1);
            conv_tile<128, 256, 8, 28, 28, 0><<<g3a, 256, 0, stream>>>(
                x2p, nullptr, nullptr, 0, w3a, b3a, x3a);
            dim3 g3b(64, 16, 1);
            conv_tile<256, 256, 8, 28, 28, 1><<<g3b, 256, 0, stream>>>(
                x3a, nullptr, nullptr, 0, w3b, b3b, x3bp);
            dim3 g4a(8, 32, 1);
            conv_tile<256, 512, 4, 14, 14, 0><<<g4a, 256, 0, stream>>>(
                x3bp, nullptr, nullptr, 0, w4a, b4a, x4a);
            dim3 g4b(8, 32, 1);
            conv_tile<512, 512, 4, 14, 14, 1><<<g4b, 256, 0, stream>>>(
                x4a, nullptr, nullptr, 0, w4b, b4b, x4bp);
            dim3 g5a(1, 32, 1);
            conv_tile<512, 512, 2, 7, 7, 0><<<g5a, 256, 0, stream>>>(
                x4bp, nullptr, nullptr, 0, w5a, b5a, x5a);
            dim3 g5b(1, 32, 1);
            conv_tile<512, 512, 2, 7, 7, 3><<<g5b, 256, 0, stream>>>(
                x5a, nullptr, nullptr, 0, w5b, b5b, x5bp);
            fc_kernel<<<(4096 * 64 + 255) / 256, 256, 0, stream>>>(x5bp, w6, b6, fc6o, 8192, 4096, 4096);
            fc_kernel<<<(4096 * 64 + 255) / 256, 256, 0, stream>>>(fc6o, w7, b7,
                                                                   feat + (size_t)clip * 4096, 4096, 4096, 4096);
        }
        dots_kernel<<<168, 256, 0, stream>>>(feat, dotsb);
        sinkhorn_kernel<<<1, 64, 0, stream>>>(dotsb, out);
    }
}

// Round 3
// 10813.937 us; speedup vs baseline: 18.8173x; 3.9835x over previous
//
#include <hip/hip_runtime.h>
#include <hip/hip_bf16.h>
#include <cmath>

#define BN_SCALE_F 0.9999950000374997f

typedef __attribute__((ext_vector_type(8))) short short8;
typedef __attribute__((ext_vector_type(4))) float floatx4;

static __device__ __forceinline__ ushort f2bf(float x) {
    union { float f; unsigned u; } c; c.f = x;
    unsigned r = (c.u + 0x7FFFu + ((c.u >> 16) & 1u)) >> 16;
    return (ushort)r;
}
static __device__ __forceinline__ float bf2f(ushort h) {
    union { unsigned u; float f; } c; c.u = ((unsigned)h) << 16;
    return c.f;
}

// ---------------------------------------------------------------------------
// Weight repack: OIDHW fp32 [CO][CI][27] -> [CO][27][CI] bf16 hi/lo planes
// ---------------------------------------------------------------------------
__global__ __launch_bounds__(256) void repack_kernel(
    const float* __restrict__ w, ushort* __restrict__ oh, ushort* __restrict__ ol,
    int CI, int total)
{
    int idx = blockIdx.x * 256 + threadIdx.x;
    if (idx >= total) return;
    int ci = idx % CI;
    int t  = (idx / CI) % 27;
    int co = idx / (CI * 27);
    float v = w[((size_t)co * CI + ci) * 27 + t];
    ushort h = f2bf(v);
    oh[idx] = h;
    ol[idx] = f2bf(v - bf2f(h));
}

// ---------------------------------------------------------------------------
// conv1: fp32 compute (Cin=3), BN+ReLU+pool(1,2,2), writes NDHWC bf16 hi/lo.
// Block 16co x 16sp, conv region (2,8,8), input patch (4,10,10) in LDS.
// ---------------------------------------------------------------------------
__global__ __launch_bounds__(256) void conv1_ndhwc(
    const float* __restrict__ sup, const float* __restrict__ qry, int clipBase,
    const float* __restrict__ wgt, const float* __restrict__ bias,
    ushort* __restrict__ outH, ushort* __restrict__ outL)
{
    __shared__ float sIn[4][10][12];
    __shared__ float sW[16][28];
    const int tid = threadIdx.x;
    const int bw = blockIdx.x % 14;
    const int bh = (blockIdx.x / 14) % 14;
    const int bd = blockIdx.x / 196;
    const int coL = tid >> 4;
    const int co  = blockIdx.y * 16 + coL;
    const int sp  = tid & 15;
    const int sh = sp >> 2, sw = sp & 3;
    const int n = blockIdx.z;
    const int clip = clipBase + n;
    const float* src = (clip < 12) ? (sup + (size_t)clip * 602112)
                                   : (qry + (size_t)(clip - 12) * 602112);
    const int d0 = 2 * bd, h0 = 8 * bh, w0 = 8 * bw;

    float acc[8] = {0.f,0.f,0.f,0.f,0.f,0.f,0.f,0.f};
    for (int ci = 0; ci < 3; ci++) {
        for (int t = tid; t < 832; t += 256) {
            if (t < 400) {
                int pd = t / 100; int rem = t - pd * 100;
                int ph = rem / 10; int pw = rem - ph * 10;
                int gd = d0 - 1 + pd, gh = h0 - 1 + ph, gw = w0 - 1 + pw;
                float v = 0.f;
                if ((unsigned)gd < 16u && (unsigned)gh < 112u && (unsigned)gw < 112u)
                    v = src[(size_t)gd * 37632 + ci * 12544 + gh * 112 + gw];
                sIn[pd][ph][pw] = v;
            } else {
                int t2 = t - 400;
                if (t2 < 432) {
                    int cl = t2 / 27, k = t2 - cl * 27;
                    sW[cl][k] = wgt[((size_t)(blockIdx.y * 16 + cl) * 3 + ci) * 27 + k];
                }
            }
        }
        __syncthreads();
        float wr[27];
#pragma unroll
        for (int k = 0; k < 27; k++) wr[k] = sW[coL][k];
#pragma unroll
        for (int dd = 0; dd < 4; dd++) {
            float qv[16];
#pragma unroll
            for (int hh = 0; hh < 4; hh++)
#pragma unroll
                for (int ww = 0; ww < 4; ww++)
                    qv[hh * 4 + ww] = sIn[dd][2 * sh + hh][2 * sw + ww];
#pragma unroll
            for (int kd = 0; kd < 3; kd++) {
                int deltad = dd - kd;
                if (deltad < 0 || deltad > 1) continue;
#pragma unroll
                for (int kh = 0; kh < 3; kh++)
#pragma unroll
                    for (int kw = 0; kw < 3; kw++) {
                        float wv = wr[kd * 9 + kh * 3 + kw];
#pragma unroll
                        for (int dh = 0; dh < 2; dh++)
#pragma unroll
                            for (int dw = 0; dw < 2; dw++)
                                acc[deltad * 4 + dh * 2 + dw] =
                                    fmaf(wv, qv[(dh + kh) * 4 + (dw + kw)],
                                         acc[deltad * 4 + dh * 2 + dw]);
                    }
            }
        }
        __syncthreads();
    }
    const float b = __ldg(bias + co);
    const int oh = 4 * bh + sh, ow = 4 * bw + sw;
#pragma unroll
    for (int dd = 0; dd < 2; dd++) {
        float m = 0.f;
#pragma unroll
        for (int k = 0; k < 4; k++) m = fmaxf(m, (acc[dd * 4 + k] + b) * BN_SCALE_F);
        size_t idx = ((((size_t)n * 16 + (d0 + dd)) * 56 + oh) * 56 + ow) * 64 + co;
        ushort h = f2bf(m);
        outH[idx] = h;
        outL[idx] = f2bf(m - bf2f(h));
    }
}

// ---------------------------------------------------------------------------
// MFMA implicit-GEMM 3x3x3 conv, bf16 hi/lo split (3-product), NDHWC.
// Block: 64co x 256sp (spatial box 4x8x8); wave: 64co x 64sp.
// MODE 0: 'a' conv+ReLU -> NDHWC hi/lo
// MODE 1: 'b' conv+BN+ReLU+pool2 -> NDHWC hi/lo
// MODE 2: 'b' conv+BN+ReLU+pool2 -> NCDHW fp32
// ---------------------------------------------------------------------------
template<int CIN,int COUT,int D,int H,int W,int MODE>
__global__ __launch_bounds__(256,1) void conv_mfma(
    const ushort* __restrict__ inH, const ushort* __restrict__ inL,
    const ushort* __restrict__ wH,  const ushort* __restrict__ wL,
    const float* __restrict__ bias,
    ushort* __restrict__ outH, ushort* __restrict__ outL, float* __restrict__ outF)
{
    constexpr int TW = (W + 7) / 8;
    constexpr int TH = (H + 7) / 8;
    __shared__ ushort sMem[19200 * 2 + 6144 * 2];
    ushort* sPH = sMem;
    ushort* sPL = sMem + 19200;
    ushort* sWH = sMem + 38400;
    ushort* sWL = sMem + 44544;

    const int tid = threadIdx.x;
    const int lane = tid & 63;
    const int wv = tid >> 6;
    const int n15 = lane & 15;
    const int g4 = lane >> 4;
    const int tw = blockIdx.x % TW;
    const int th = (blockIdx.x / TW) % TH;
    const int td = blockIdx.x / (TW * TH);
    const int coG0 = blockIdx.y * 64;
    const int n = blockIdx.z;

    int sdv[4], shv[4], swv[4];
#pragma unroll
    for (int spg = 0; spg < 4; spg++) {
        int s = wv * 64 + spg * 16 + n15;
        sdv[spg] = s >> 6; shv[spg] = (s >> 3) & 7; swv[spg] = s & 7;
    }

    const size_t inBase = (size_t)n * CIN * D * H * W;

    floatx4 acc[4][4];
#pragma unroll
    for (int i = 0; i < 4; i++)
#pragma unroll
        for (int j = 0; j < 4; j++) acc[i][j] = (floatx4){0.f, 0.f, 0.f, 0.f};

    uint4 pfH[3], pfL[3];

    for (int c0 = 0; c0 < CIN; c0 += 32) {
        // stage input patch (6x10x10 x 32ci), hi & lo
        for (int t = tid; t < 2400; t += 256) {
            int pos = t >> 2, g = t & 3;
            int pd = pos / 100; int rem = pos - pd * 100;
            int ph = rem / 10;  int pw = rem - ph * 10;
            int gd = td * 4 - 1 + pd;
            int gh = th * 8 - 1 + ph;
            int gw = tw * 8 - 1 + pw;
            uint4 vh = {0u,0u,0u,0u}, vl = {0u,0u,0u,0u};
            if ((unsigned)gd < (unsigned)D && (unsigned)gh < (unsigned)H && (unsigned)gw < (unsigned)W) {
                size_t gi = inBase + (((size_t)gd * H + gh) * W + gw) * CIN + c0 + g * 8;
                vh = *(const uint4*)(inH + gi);
                vl = *(const uint4*)(inL + gi);
            }
            *(uint4*)(sPH + pos * 32 + g * 8) = vh;
            *(uint4*)(sPL + pos * 32 + g * 8) = vl;
        }
        if (c0 == 0) {
#pragma unroll
            for (int k = 0; k < 3; k++) {
                int t = tid + k * 256;
                int kw = t >> 8, col = (t >> 2) & 63, g8 = t & 3;
                size_t src = ((size_t)(coG0 + col) * 27 + kw) * CIN + g8 * 8;
                pfH[k] = *(const uint4*)(wH + src);
                pfL[k] = *(const uint4*)(wL + src);
            }
        }
        __syncthreads();

        for (int row = 0; row < 9; row++) {
            // commit prefetched weight row (3 taps x 64co x 32ci)
#pragma unroll
            for (int k = 0; k < 3; k++) {
                int t = tid + k * 256;
                int kw = t >> 8, col = (t >> 2) & 63, g8 = t & 3;
                int dst = (kw * 64 + col) * 32 + g8 * 8;
                *(uint4*)(sWH + dst) = pfH[k];
                *(uint4*)(sWL + dst) = pfL[k];
            }
            __syncthreads();
            // prefetch next row (or row0 of next chunk)
            {
                int nc0 = c0, nrow = row + 1;
                if (nrow == 9) { nrow = 0; nc0 = c0 + 32; }
                if (nc0 < CIN) {
#pragma unroll
                    for (int k = 0; k < 3; k++) {
                        int t = tid + k * 256;
                        int kw = t >> 8, col = (t >> 2) & 63, g8 = t & 3;
                        size_t src = ((size_t)(coG0 + col) * 27 + nrow * 3 + kw) * CIN + nc0 + g8 * 8;
                        pfH[k] = *(const uint4*)(wH + src);
                        pfL[k] = *(const uint4*)(wL + src);
                    }
                }
            }
            const int kd = row / 3, kh = row - kd * 3;
            int pbase[4];
#pragma unroll
            for (int spg = 0; spg < 4; spg++)
                pbase[spg] = ((sdv[spg] + kd) * 10 + shv[spg] + kh) * 10 + swv[spg];
#pragma unroll
            for (int kw = 0; kw < 3; kw++) {
                short8 Bh[4], Bl[4];
#pragma unroll
                for (int spg = 0; spg < 4; spg++) {
                    int off = (pbase[spg] + kw) * 32 + g4 * 8;
                    Bh[spg] = *(const short8*)(sPH + off);
                    Bl[spg] = *(const short8*)(sPL + off);
                }
#pragma unroll
                for (int cog = 0; cog < 4; cog++) {
                    int offA = (kw * 64 + cog * 16 + n15) * 32 + g4 * 8;
                    short8 Ah = *(const short8*)(sWH + offA);
                    short8 Al = *(const short8*)(sWL + offA);
#pragma unroll
                    for (int spg = 0; spg < 4; spg++) {
                        acc[cog][spg] = __builtin_amdgcn_mfma_f32_16x16x32_bf16(Ah, Bh[spg], acc[cog][spg], 0, 0, 0);
                        acc[cog][spg] = __builtin_amdgcn_mfma_f32_16x16x32_bf16(Ah, Bl[spg], acc[cog][spg], 0, 0, 0);
                        acc[cog][spg] = __builtin_amdgcn_mfma_f32_16x16x32_bf16(Al, Bh[spg], acc[cog][spg], 0, 0, 0);
                    }
                }
            }
            __syncthreads();
        }
    }

    // epilogue: acc -> LDS (padded) -> pooled/plain stores
    float* sEp = (float*)sMem;
#pragma unroll
    for (int cog = 0; cog < 4; cog++)
#pragma unroll
        for (int spg = 0; spg < 4; spg++) {
            int sp = wv * 64 + spg * 16 + n15;
#pragma unroll
            for (int r = 0; r < 4; r++) {
                int co = cog * 16 + g4 * 4 + r;
                sEp[sp * 65 + co] = acc[cog][spg][r];
            }
        }
    __syncthreads();

    const int co = tid & 63;
    const int coG = coG0 + co;
    const float b = __ldg(bias + coG);

    if constexpr (MODE == 0) {
#pragma unroll 4
        for (int i = 0; i < 64; i++) {
            int sp = i * 4 + (tid >> 6);
            int ld = sp >> 6, lh = (sp >> 3) & 7, lw = sp & 7;
            int gd = td * 4 + ld, gh = th * 8 + lh, gw = tw * 8 + lw;
            if (gh < H && gw < W) {
                float y = fmaxf(sEp[sp * 65 + co] + b, 0.f);
                size_t idx = ((((size_t)n * D + gd) * H + gh) * W + gw) * COUT + coG;
                ushort h = f2bf(y);
                outH[idx] = h;
                outL[idx] = f2bf(y - bf2f(h));
            }
        }
    } else {
        constexpr int OD = D / 2, OH = H / 2, OW = W / 2;
#pragma unroll
        for (int i = 0; i < 8; i++) {
            int pp = i * 4 + (tid >> 6);
            int ppd = pp >> 4, pph = (pp >> 2) & 3, ppw = pp & 3;
            int gpd = td * 2 + ppd, gph = th * 4 + pph, gpw = tw * 4 + ppw;
            if (gph < OH && gpw < OW) {
                float m = -1e30f;
#pragma unroll
                for (int dd = 0; dd < 2; dd++)
#pragma unroll
                    for (int dh = 0; dh < 2; dh++)
#pragma unroll
                        for (int dw = 0; dw < 2; dw++) {
                            int sp = (ppd * 2 + dd) * 64 + (pph * 2 + dh) * 8 + (ppw * 2 + dw);
                            m = fmaxf(m, sEp[sp * 65 + co]);
                        }
                float y = fmaxf((m + b) * BN_SCALE_F, 0.f);
                if constexpr (MODE == 1) {
                    size_t idx = ((((size_t)n * OD + gpd) * OH + gph) * OW + gpw) * COUT + coG;
                    ushort h = f2bf(y);
                    outH[idx] = h;
                    outL[idx] = f2bf(y - bf2f(h));
                } else {
                    size_t idx = ((((size_t)n * COUT + coG) * OD + gpd) * OH + gph) * OW + gpw;
                    outF[idx] = y;
                }
            }
        }
    }
}

// ---------------------------------------------------------------------------
// fp32 tiled conv (round-2 kernel) — used for conv5a (MODE 0) / conv5b (MODE 3)
// ---------------------------------------------------------------------------
template<int CIN,int COUT,int D,int H,int W,int MODE>
__global__ __launch_bounds__(256) void conv_tile(
    const float* __restrict__ in,
    const float* __restrict__ wgt, const float* __restrict__ bias,
    float* __restrict__ out)
{
    constexpr int PAD = (MODE == 3) ? 1 : 0;
    constexpr int OD  = (MODE == 0) ? D : D / 2;
    constexpr int OH  = (MODE == 0) ? H : (H + 2 * PAD) / 2;
    constexpr int OW  = (MODE == 0) ? W : (W + 2 * PAD) / 2;
    constexpr int TH  = (MODE == 0) ? (H + 7) / 8 : (OH + 3) / 4;
    constexpr int TW  = (MODE == 0) ? (W + 7) / 8 : (OW + 3) / 4;
    constexpr int HW  = H * W;
    constexpr int CC  = 2;

    __shared__ float sIn[CC][4][10][12];
    __shared__ float sW[CC][16][28];

    const int tid = threadIdx.x;
    const int bw = blockIdx.x % TW;
    const int bh = (blockIdx.x / TW) % TH;
    const int bd = blockIdx.x / (TW * TH);
    const int coL = tid >> 4;
    const int co  = blockIdx.y * 16 + coL;
    const int sp  = tid & 15;
    const int sh = sp >> 2, sw = sp & 3;
    const int n = blockIdx.z;

    const int d0 = 2 * bd, h0 = 8 * bh - PAD, w0 = 8 * bw - PAD;
    const int ht = h0 + 2 * sh, wt = w0 + 2 * sw;

    const float* src = in + (size_t)n * CIN * D * HW;

    float acc[8] = {0.f,0.f,0.f,0.f,0.f,0.f,0.f,0.f};

    for (int ci0 = 0; ci0 < CIN; ci0 += CC) {
        for (int t = tid; t < CC * 400 + CC * 432; t += 256) {
            if (t < CC * 400) {
                int c = t / 400, r = t % 400;
                int pd = r / 100, ph = (r / 10) % 10, pw = r % 10;
                int gd = d0 - 1 + pd, gh = h0 - 1 + ph, gw = w0 - 1 + pw;
                float v = 0.f;
                if (gd >= 0 && gd < D && gh >= 0 && gh < H && gw >= 0 && gw < W)
                    v = src[(size_t)(ci0 + c) * D * HW + gd * HW + gh * W + gw];
                sIn[c][pd][ph][pw] = v;
            } else {
                int t2 = t - CC * 400;
                int c = t2 / 432, r = t2 % 432;
                int cl = r / 27, k = r % 27;
                sW[c][cl][k] = wgt[((size_t)(blockIdx.y * 16 + cl) * CIN + (ci0 + c)) * 27 + k];
            }
        }
        __syncthreads();
        for (int c = 0; c < CC; c++) {
            float wr[27];
#pragma unroll
            for (int k = 0; k < 27; k++) wr[k] = sW[c][coL][k];
#pragma unroll
            for (int dd = 0; dd < 4; dd++) {
                float qv[16];
#pragma unroll
                for (int hh = 0; hh < 4; hh++)
#pragma unroll
                    for (int ww = 0; ww < 4; ww++)
                        qv[hh * 4 + ww] = sIn[c][dd][2 * sh + hh][2 * sw + ww];
#pragma unroll
                for (int kd = 0; kd < 3; kd++) {
                    int deltad = dd - kd;
                    if (deltad < 0 || deltad > 1) continue;
#pragma unroll
                    for (int kh = 0; kh < 3; kh++)
#pragma unroll
                        for (int kw = 0; kw < 3; kw++) {
                            float wv = wr[kd * 9 + kh * 3 + kw];
#pragma unroll
                            for (int dh = 0; dh < 2; dh++)
#pragma unroll
                                for (int dw = 0; dw < 2; dw++)
                                    acc[deltad * 4 + dh * 2 + dw] =
                                        fmaf(wv, qv[(dh + kh) * 4 + (dw + kw)],
                                             acc[deltad * 4 + dh * 2 + dw]);
                        }
                }
            }
        }
        __syncthreads();
    }

    const float b = __ldg(bias + co);
    if constexpr (MODE == 0) {
#pragma unroll
        for (int dd = 0; dd < 2; dd++) {
            int d = d0 + dd; if (d >= D) continue;
#pragma unroll
            for (int dh = 0; dh < 2; dh++) {
                int h = ht + dh; if (h < 0 || h >= H) continue;
#pragma unroll
                for (int dw = 0; dw < 2; dw++) {
                    int w = wt + dw; if (w < 0 || w >= W) continue;
                    out[(((size_t)n * COUT + co) * D + d) * HW + h * W + w] =
                        fmaxf(acc[dd * 4 + dh * 2 + dw] + b, 0.f);
                }
            }
        }
    } else {
        int oh = 4 * bh + sh, ow = 4 * bw + sw;
        if (oh < OH && ow < OW) {
            float m = 0.f;
#pragma unroll
            for (int dd2 = 0; dd2 < 2; dd2++)
#pragma unroll
                for (int dh = 0; dh < 2; dh++) {
                    int h = ht + dh; if (PAD && (h < 0 || h >= H)) continue;
#pragma unroll
                    for (int dw = 0; dw < 2; dw++) {
                        int w = wt + dw; if (PAD && (w < 0 || w >= W)) continue;
                        m = fmaxf(m, (acc[dd2 * 4 + dh * 2 + dw] + b) * BN_SCALE_F);
                    }
                }
            out[(((size_t)n * COUT + co) * OD + bd) * (OH * OW) + oh * OW + ow] = m;
        }
    }
}

// ---------------------------------------------------------------------------
__global__ __launch_bounds__(256) void fc_kernel(
    const float* __restrict__ x, const float* __restrict__ wgt,
    const float* __restrict__ bias, float* __restrict__ out,
    int K, int Cout, int total)
{
    int gt = blockIdx.x * 256 + threadIdx.x;
    int wid = gt >> 6;
    int lane = gt & 63;
    if (wid >= total) return;
    int co = wid % Cout; int n = wid / Cout;
    const float4* xp = (const float4*)(x + (size_t)n * K);
    const float4* wp = (const float4*)(wgt + (size_t)co * K);
    int K4 = K >> 2;
    float s = 0.f;
    for (int k = lane; k < K4; k += 64) {
        float4 a = __ldg(xp + k), b = __ldg(wp + k);
        s += a.x * b.x + a.y * b.y + a.z * b.z + a.w * b.w;
    }
#pragma unroll
    for (int off = 32; off > 0; off >>= 1) s += __shfl_down(s, off, 64);
    if (lane == 0) {
        float y = (s + __ldg(bias + co)) * BN_SCALE_F;
        out[wid] = fmaxf(y, 0.f);
    }
}

__global__ __launch_bounds__(256) void dots_kernel(
    const float* __restrict__ feat, float* __restrict__ dots)
{
    int task = blockIdx.x; int tid = threadIdx.x;
    int ra, rb;
    if (task < 24) { ra = task; rb = task; }
    else {
        int t = task - 24;
        int q = t / 48; int r = t % 48;
        int i = r / 12; int s = (r % 12) / 4; int j = r % 4;
        ra = 12 + q * 4 + i;
        rb = s * 4 + j;
    }
    const float4* A = (const float4*)(feat + (size_t)ra * 4096);
    const float4* B = (const float4*)(feat + (size_t)rb * 4096);
    float acc = 0.f;
    for (int k = tid; k < 1024; k += 256) {
        float4 a = A[k], b = B[k];
        acc += a.x * b.x + a.y * b.y + a.z * b.z + a.w * b.w;
    }
#pragma unroll
    for (int off = 32; off > 0; off >>= 1) acc += __shfl_down(acc, off, 64);
    __shared__ float red[4];
    if ((tid & 63) == 0) red[tid >> 6] = acc;
    __syncthreads();
    if (tid == 0) dots[task] = red[0] + red[1] + red[2] + red[3];
}

__global__ __launch_bounds__(64) void sinkhorn_kernel(
    const float* __restrict__ dots, float* __restrict__ out)
{
    int t = threadIdx.x;
    if (t >= 9) return;
    int q = t / 3, s = t % 3;
    float Km[16], sem[16];
#pragma unroll
    for (int i = 0; i < 4; i++) {
        float nq = sqrtf(dots[12 + q * 4 + i]) + 1e-8f;
#pragma unroll
        for (int j = 0; j < 4; j++) {
            float ns = sqrtf(dots[s * 4 + j]) + 1e-8f;
            float d = dots[24 + q * 48 + i * 12 + s * 4 + j];
            float c = 1.0f - d / (nq * ns);
            float ti = i * 0.25f, tj = j * 0.25f;
            float d2 = (ti - tj) * (ti - tj);
            float pc = expf(-1.0f / (d2 + 1.0f));
            sem[i * 4 + j] = c;
            Km[i * 4 + j] = expf(-7.0f * (c + 0.4f * pc));
        }
    }
    float u[4] = {0.25f, 0.25f, 0.25f, 0.25f}, v[4];
    for (int it = 0; it < 100; it++) {
#pragma unroll
        for (int j = 0; j < 4; j++) {
            float sj = Km[j] * u[0] + Km[4 + j] * u[1] + Km[8 + j] * u[2] + Km[12 + j] * u[3];
            v[j] = 0.25f / (sj + 1e-9f);
        }
#pragma unroll
        for (int i = 0; i < 4; i++) {
            float si = Km[i * 4] * v[0] + Km[i * 4 + 1] * v[1] + Km[i * 4 + 2] * v[2] + Km[i * 4 + 3] * v[3];
            u[i] = 0.25f / (si + 1e-9f);
        }
    }
#pragma unroll
    for (int j = 0; j < 4; j++) {
        float sj = Km[j] * u[0] + Km[4 + j] * u[1] + Km[8 + j] * u[2] + Km[12 + j] * u[3];
        v[j] = 0.25f / (sj + 1e-9f);
    }
    float tc = 0.f;
#pragma unroll
    for (int i = 0; i < 4; i++)
#pragma unroll
        for (int j = 0; j < 4; j++)
            tc += u[i] * Km[i * 4 + j] * v[j] * sem[i * 4 + j];
    out[q * 3 + s] = -tc;
}

// ---------------------------------------------------------------------------
extern "C" void kernel_launch(void* const* d_in, const int* in_sizes, int n_in,
                              void* d_out, int out_size, void* d_ws, size_t ws_size,
                              hipStream_t stream)
{
    const float* sup = (const float*)d_in[0];
    const float* qry = (const float*)d_in[1];
    const float* w1  = (const float*)d_in[2];  const float* b1  = (const float*)d_in[3];
    const float* w2  = (const float*)d_in[4];  const float* b2  = (const float*)d_in[5];
    const float* w3a = (const float*)d_in[6];  const float* b3a = (const float*)d_in[7];
    const float* w3b = (const float*)d_in[8];  const float* b3b = (const float*)d_in[9];
    const float* w4a = (const float*)d_in[10]; const float* b4a = (const float*)d_in[11];
    const float* w4b = (const float*)d_in[12]; const float* b4b = (const float*)d_in[13];
    const float* w5a = (const float*)d_in[14]; const float* b5a = (const float*)d_in[15];
    const float* w5b = (const float*)d_in[16]; const float* b5b = (const float*)d_in[17];
    const float* w6  = (const float*)d_in[18]; const float* b6  = (const float*)d_in[19];
    const float* w7  = (const float*)d_in[20]; const float* b7  = (const float*)d_in[21];
    float* out = (float*)d_out;

    char* wsB = (char*)d_ws;
    size_t off = 0;
    auto carve = [&](size_t bytes) -> char* {
        char* p = wsB + off;
        off = (off + bytes + 255) & ~(size_t)255;
        return p;
    };

    // repacked weights (bf16 hi/lo), [CO][27][CI]
    const int RW2 = 128 * 27 * 64, RW3a = 256 * 27 * 128, RW3b = 256 * 27 * 256;
    const int RW4a = 512 * 27 * 256, RW4b = 512 * 27 * 512;
    ushort* w2H  = (ushort*)carve((size_t)RW2 * 2);  ushort* w2L  = (ushort*)carve((size_t)RW2 * 2);
    ushort* w3aH = (ushort*)carve((size_t)RW3a * 2); ushort* w3aL = (ushort*)carve((size_t)RW3a * 2);
    ushort* w3bH = (ushort*)carve((size_t)RW3b * 2); ushort* w3bL = (ushort*)carve((size_t)RW3b * 2);
    ushort* w4aH = (ushort*)carve((size_t)RW4a * 2); ushort* w4aL = (ushort*)carve((size_t)RW4a * 2);
    ushort* w4bH = (ushort*)carve((size_t)RW4b * 2); ushort* w4bL = (ushort*)carve((size_t)RW4b * 2);

    // persistent tail (fp32)
    float* x4b24 = (float*)carve((size_t)24 * 50176 * 4);
    float* x5a24 = (float*)carve((size_t)24 * 50176 * 4);
    float* x5b24 = (float*)carve((size_t)24 * 8192 * 4);
    float* fc6o  = (float*)carve((size_t)24 * 4096 * 4);
    float* feat  = (float*)carve((size_t)24 * 4096 * 4);
    float* dotsb = (float*)carve(256 * 4);

    const size_t fixed = off;
    const long long P1 = 3211264LL, P2 = 802816LL;      // elems per clip (regions A/B)
    const long long perG = (P1 + P2) * 2 * 2;           // bytes/clip: hi+lo planes
    int G = 1;
    const int cands[8] = {24, 12, 8, 6, 4, 3, 2, 1};
    for (int k = 0; k < 8; k++) {
        if (fixed + (size_t)(perG * cands[k]) + 4096 <= ws_size) { G = cands[k]; break; }
    }
    ushort* AH = (ushort*)carve((size_t)G * P1 * 2);
    ushort* AL = (ushort*)carve((size_t)G * P1 * 2);
    ushort* BH = (ushort*)carve((size_t)G * P2 * 2);
    ushort* BL = (ushort*)carve((size_t)G * P2 * 2);

    // --- weight repack (once per call) ---
    repack_kernel<<<(RW2  + 255) / 256, 256, 0, stream>>>(w2,  w2H,  w2L,  64,  RW2);
    repack_kernel<<<(RW3a + 255) / 256, 256, 0, stream>>>(w3a, w3aH, w3aL, 128, RW3a);
    repack_kernel<<<(RW3b + 255) / 256, 256, 0, stream>>>(w3b, w3bH, w3bL, 256, RW3b);
    repack_kernel<<<(RW4a + 255) / 256, 256, 0, stream>>>(w4a, w4aH, w4aL, 256, RW4a);
    repack_kernel<<<(RW4b + 255) / 256, 256, 0, stream>>>(w4b, w4bH, w4bL, 512, RW4b);

    for (int base = 0; base < 24; base += G) {
        conv1_ndhwc<<<dim3(1568, 4, G), 256, 0, stream>>>(sup, qry, base, w1, b1, AH, AL);
        conv_mfma<64, 128, 16, 56, 56, 1><<<dim3(196, 2, G), 256, 0, stream>>>(
            AH, AL, w2H, w2L, b2, BH, BL, nullptr);
        conv_mfma<128, 256, 8, 28, 28, 0><<<dim3(32, 4, G), 256, 0, stream>>>(
            BH, BL, w3aH, w3aL, b3a, AH, AL, nullptr);
        conv_mfma<256, 256, 8, 28, 28, 1><<<dim3(32, 4, G), 256, 0, stream>>>(
            AH, AL, w3bH, w3bL, b3b, BH, BL, nullptr);
        conv_mfma<256, 512, 4, 14, 14, 0><<<dim3(4, 8, G), 256, 0, stream>>>(
            BH, BL, w4aH, w4aL, b4a, AH, AL, nullptr);
        conv_mfma<512, 512, 4, 14, 14, 2><<<dim3(4, 8, G), 256, 0, stream>>>(
            AH, AL, w4bH, w4bL, b4b, nullptr, nullptr, x4b24 + (size_t)base * 50176);
    }

    conv_tile<512, 512, 2, 7, 7, 0><<<dim3(1, 32, 24), 256, 0, stream>>>(x4b24, w5a, b5a, x5a24);
    conv_tile<512, 512, 2, 7, 7, 3><<<dim3(1, 32, 24), 256, 0, stream>>>(x5a24, w5b, b5b, x5b24);
    int t6 = 24 * 4096;
    fc_kernel<<<(t6 * 64 + 255) / 256, 256, 0, stream>>>(x5b24, w6, b6, fc6o, 8192, 4096, t6);
    fc_kernel<<<(t6 * 64 + 255) / 256, 256, 0, stream>>>(fc6o, w7, b7, feat, 4096, 4096, t6);
    dots_kernel<<<168, 256, 0, stream>>>(feat, dotsb);
    sinkhorn_kernel<<<1, 64, 0, stream>>>(dotsb, out);
}